// Round 5
// baseline (567.437 us; speedup 1.0000x reference)
//
#include <hip/hip_runtime.h>
#include <math.h>

// ---------------------------------------------------------------------------
// SGCN forward — R5: split pull-gather (bf16 tables) + MFMA dense layers.
//
// R4 post-mortem: fused layer kernels were VALU-bound (72% VALUBusy), 2/3 of
// it matmul-shaped FMA+unpack. R5: gather_k writes per-node [ap|an] bf16
// rows; gemm_k does [agg|feat] @ B' (192x64, zero-structured) with
// mfma_f32_16x16x32_bf16, B-fragments in VGPRs, A-fragments loaded directly
// from global (rows are k-contiguous = fragment layout), epilogue transposes
// C through LDS (layer1 -> z bf16, layer2 -> out fp32).
// ---------------------------------------------------------------------------

typedef __attribute__((ext_vector_type(8))) __bf16 bf16x8;
typedef __attribute__((ext_vector_type(4))) float f32x4;

__device__ inline unsigned bfpack(float lo, float hi) {
    unsigned a = __float_as_uint(lo), b = __float_as_uint(hi);
    a += 0x7fffu + ((a >> 16) & 1u);          // RNE to bf16
    b += 0x7fffu + ((b >> 16) & 1u);
    return (a >> 16) | (b & 0xffff0000u);
}
__device__ inline float bflo(unsigned p) { return __uint_as_float(p << 16); }
__device__ inline float bfhi(unsigned p) { return __uint_as_float(p & 0xffff0000u); }

__device__ inline float tanh_fast(float x) {
    // tanh(x) = 1 - 2/(e^{2x}+1); v_exp_f32 + v_rcp_f32
    float e = __builtin_amdgcn_exp2f(x * 2.8853900817779268f);
    return 1.0f - 2.0f * __builtin_amdgcn_rcpf(e + 1.0f);
}

__device__ inline bf16x8 as_frag(uint4 u) { return __builtin_bit_cast(bf16x8, u); }

// ------------------------------- CSR build ---------------------------------

__global__ void __launch_bounds__(256) hist_k(
    const int* __restrict__ pos, const int* __restrict__ neg,
    int* __restrict__ deg, int E, int n)
{
    int e = blockIdx.x * 256 + threadIdx.x;
    if (e < E)            atomicAdd(&deg[pos[E + e]], 1);
    else if (e < 2 * E)   atomicAdd(&deg[n + neg[E + (e - E)]], 1);
}

__global__ void __launch_bounds__(256) scan1_k(
    const int* __restrict__ deg, int* __restrict__ cur,
    int* __restrict__ bsum, int n2)
{
    __shared__ int s[256];
    int tid = threadIdx.x;
    int i = blockIdx.x * 256 + tid;
    int v = (i < n2) ? deg[i] : 0;
    s[tid] = v;
    __syncthreads();
    for (int off = 1; off < 256; off <<= 1) {
        int t = (tid >= off) ? s[tid - off] : 0;
        __syncthreads();
        s[tid] += t;
        __syncthreads();
    }
    if (i < n2) cur[i] = s[tid] - v;
    if (tid == 255) bsum[blockIdx.x] = s[255];
}

__global__ void __launch_bounds__(1024) scan2_k(int* __restrict__ bsum, int nb)
{
    __shared__ int s[1024];
    int tid = threadIdx.x;
    int v = (tid < nb) ? bsum[tid] : 0;
    s[tid] = v;
    __syncthreads();
    for (int off = 1; off < 1024; off <<= 1) {
        int t = (tid >= off) ? s[tid - off] : 0;
        __syncthreads();
        s[tid] += t;
        __syncthreads();
    }
    if (tid < nb) bsum[tid] = s[tid] - v;
}

__global__ void __launch_bounds__(256) scan3_k(
    int* __restrict__ cur, const int* __restrict__ bsum, int n2)
{
    int i = blockIdx.x * 256 + threadIdx.x;
    if (i < n2) cur[i] += bsum[blockIdx.x];
}

// XCD-partitioned fill (R4): block b serves dst-partition (b & 7).
__global__ void __launch_bounds__(256) fill_k(
    const int* __restrict__ pos, const int* __restrict__ neg,
    int* __restrict__ cur, int* __restrict__ col, int E, int n,
    int blocksPerPart)
{
    int part = blockIdx.x & 7;
    int wb   = blockIdx.x >> 3;
    int n2 = 2 * n;
    int lo = (int)(((long long)n2 * part) >> 3);
    int hi = (int)(((long long)n2 * (part + 1)) >> 3);
    int stride = blocksPerPart * 256;
    for (int e = wb * 256 + (int)threadIdx.x; e < 2 * E; e += stride) {
        int node;
        if (e < E) node = pos[E + e];
        else       node = n + neg[E + (e - E)];
        if (node >= lo && node < hi) {
            int src = (e < E) ? pos[e] : neg[e - E];
            int slot = atomicAdd(&cur[node], 1);
            col[slot] = src;
        }
    }
}

// fp32 -> packed bf16 pairs
__global__ void __launch_bounds__(256) cvt_k(
    const float2* __restrict__ xf, unsigned* __restrict__ xb, int m)
{
    int i = blockIdx.x * 256 + threadIdx.x;
    if (i < m) { float2 v = xf[i]; xb[i] = bfpack(v.x, v.y); }
}

// ----------------------------- pull gather ---------------------------------
// One wave per node (grid-stride). lane = 16g+f: group g handles edges
// p0+4k+g, f indexes an 8-byte (4-feature) chunk of the 128B bf16 row.
// Writes Aout[node] = [mean_pos(64 bf16) | mean_neg(64 bf16)]  (64 uints).
__global__ void __launch_bounds__(256, 8) gather_k(
    const unsigned* __restrict__ tab,   // n x 32 uints (bf16 pairs)
    const int* __restrict__ cur, const int* __restrict__ col,
    unsigned* __restrict__ Aout,        // n x 64 uints
    int n)
{
    int tid = threadIdx.x;
    int wave = tid >> 6, lane = tid & 63, g = lane >> 4, f = lane & 15;
    int stride = gridDim.x * 4;
    for (int node = blockIdx.x * 4 + wave; node < n; node += stride) {
        int p0 = node ? cur[node - 1] : 0;
        int p1 = cur[node];
        int q0 = cur[n + node - 1];     // node==0 -> cur[n-1] == E
        int q1 = cur[n + node];
        float a0 = 0.f, a1 = 0.f, a2 = 0.f, a3 = 0.f;
        float b0 = 0.f, b1 = 0.f, b2 = 0.f, b3 = 0.f;
        #pragma unroll 2
        for (int it = p0 + g; it < p1; it += 4) {
            int s = col[it];
            uint2 t = *(const uint2*)(tab + (size_t)s * 32 + 2 * f);
            a0 += bflo(t.x); a1 += bfhi(t.x); a2 += bflo(t.y); a3 += bfhi(t.y);
        }
        #pragma unroll 2
        for (int it = q0 + g; it < q1; it += 4) {
            int s = col[it];
            uint2 t = *(const uint2*)(tab + (size_t)s * 32 + 2 * f);
            b0 += bflo(t.x); b1 += bfhi(t.x); b2 += bflo(t.y); b3 += bfhi(t.y);
        }
        a0 += __shfl_xor(a0, 16); a1 += __shfl_xor(a1, 16);
        a2 += __shfl_xor(a2, 16); a3 += __shfl_xor(a3, 16);
        b0 += __shfl_xor(b0, 16); b1 += __shfl_xor(b1, 16);
        b2 += __shfl_xor(b2, 16); b3 += __shfl_xor(b3, 16);
        a0 += __shfl_xor(a0, 32); a1 += __shfl_xor(a1, 32);
        a2 += __shfl_xor(a2, 32); a3 += __shfl_xor(a3, 32);
        b0 += __shfl_xor(b0, 32); b1 += __shfl_xor(b1, 32);
        b2 += __shfl_xor(b2, 32); b3 += __shfl_xor(b3, 32);
        float rp = 1.0f / (float)max(p1 - p0, 1);
        float rq = 1.0f / (float)max(q1 - q0, 1);
        if (g == 0) {
            uint2 o; o.x = bfpack(a0 * rp, a1 * rp); o.y = bfpack(a2 * rp, a3 * rp);
            *(uint2*)(Aout + (size_t)node * 64 + 2 * f) = o;
        } else if (g == 1) {
            uint2 o; o.x = bfpack(b0 * rq, b1 * rq); o.y = bfpack(b2 * rq, b3 * rq);
            *(uint2*)(Aout + (size_t)node * 64 + 32 + 2 * f) = o;
        }
    }
}

// ------------------------------ MFMA dense ---------------------------------
// A(node) = [agg(128 bf16) from Abuf | feat(64 bf16) from T]  (K=192)
// B'(192x64) zero-structured from Wp/Wn, staged in LDS (n-major, stride 200),
// fragments then held in VGPRs. Wave = 16 nodes x 64 cols = 4 N-tiles x
// 6 K-tiles of mfma_f32_16x16x32_bf16.
template<int LAYER>
__global__ void __launch_bounds__(256, 2) gemm_k(
    const unsigned* __restrict__ A,      // n x 64 uints  [agg_p|agg_n]
    const unsigned* __restrict__ T,      // n x 32 uints  (x or z bf16)
    const float* __restrict__ Wp, const float* __restrict__ bp,
    const float* __restrict__ Wn, const float* __restrict__ bn,
    void* __restrict__ outv, int n)
{
    __shared__ unsigned short Bl[64 * 200];   // 25.6 KB
    __shared__ float Cs[4][16 * 68];          // 17.4 KB, per-wave C transpose
    int tid = threadIdx.x;
    for (int idx = tid; idx < 64 * 192; idx += 256) {
        int k = idx >> 6, nn = idx & 63;
        float v = 0.f;
        if (LAYER == 1) {
            // cols<32: [ap rows 0..63 | 0 | x rows 64..127] of W1p
            // cols>=32:[0 | an rows 0..63 | x rows 64..127] of W1n
            if (nn < 32) { if (k < 64) v = Wp[k * 32 + nn];
                           else if (k >= 128) v = Wp[(k - 64) * 32 + nn]; }
            else         { if (k >= 64) v = Wn[(k - 64) * 32 + (nn - 32)]; }
        } else {
            // cols<32 (out_p): Ap[0:32]@k0..31, An[32:64]@k96..127, z[0:32]@k128..159
            // cols>=32(out_n): Ap[32:64]@k32..63, An[0:32]@k64..95, z[32:64]@k160..191
            if (nn < 32) { if (k < 32) v = Wp[k * 32 + nn];
                           else if (k >= 96 && k < 160) v = Wp[(k - 64) * 32 + nn]; }
            else         { if (k >= 32 && k < 96) v = Wn[(k - 32) * 32 + (nn - 32)];
                           else if (k >= 160) v = Wn[(k - 96) * 32 + (nn - 32)]; }
        }
        unsigned u = __float_as_uint(v);
        u += 0x7fffu + ((u >> 16) & 1u);
        Bl[nn * 200 + k] = (unsigned short)(u >> 16);
    }
    __syncthreads();

    int wave = tid >> 6, lane = tid & 63;
    int lm = lane & 15, lg = lane >> 4;

    bf16x8 Bf[4][6];
    #pragma unroll
    for (int t = 0; t < 4; ++t)
        #pragma unroll
        for (int s = 0; s < 6; ++s)
            Bf[t][s] = *(const bf16x8*)&Bl[(t * 16 + lm) * 200 + s * 32 + lg * 8];

    float bias[4];
    #pragma unroll
    for (int t = 0; t < 4; ++t) {
        int nc = t * 16 + lm;
        bias[t] = (nc < 32) ? bp[nc] : bn[nc - 32];
    }

    float* Cw = Cs[wave];
    int ntiles = (n + 15) >> 4;
    for (int tile = blockIdx.x * 4 + wave; tile < ntiles; tile += gridDim.x * 4) {
        int node0 = tile * 16;
        int ra = min(node0 + lm, n - 1);          // A-frag: m = lane&15
        const uint4* Arow = (const uint4*)(A + (size_t)ra * 64);
        const uint4* Trow = (const uint4*)(T + (size_t)ra * 32);
        bf16x8 Af[6];
        #pragma unroll
        for (int s = 0; s < 4; ++s) Af[s] = as_frag(Arow[s * 4 + lg]);
        #pragma unroll
        for (int s = 0; s < 2; ++s) Af[4 + s] = as_frag(Trow[s * 4 + lg]);

        #pragma unroll
        for (int t = 0; t < 4; ++t) {
            f32x4 c = {0.f, 0.f, 0.f, 0.f};
            #pragma unroll
            for (int s = 0; s < 6; ++s)
                c = __builtin_amdgcn_mfma_f32_16x16x32_bf16(Af[s], Bf[t][s], c, 0, 0, 0);
            // C/D: node = lg*4 + r, col = t*16 + lm
            #pragma unroll
            for (int r = 0; r < 4; ++r)
                Cw[(lg * 4 + r) * 68 + t * 16 + lm] = tanh_fast(c[r] + bias[t]);
        }
        __builtin_amdgcn_wave_barrier();
        if (LAYER == 1) {
            unsigned* zb = (unsigned*)outv;
            #pragma unroll
            for (int i = 0; i < 8; ++i) {
                int nn = 2 * i + (lane >> 5), cc = lane & 31;
                int node = node0 + nn;
                if (node < n) {
                    float2 rd = *(const float2*)&Cw[nn * 68 + 2 * cc];
                    zb[(size_t)node * 32 + cc] = bfpack(rd.x, rd.y);
                }
            }
        } else {
            float* out = (float*)outv;
            #pragma unroll
            for (int i = 0; i < 16; ++i) {
                int node = node0 + i;
                if (node < n) out[(size_t)node * 64 + lane] = Cw[i * 68 + lane];
            }
        }
        __builtin_amdgcn_wave_barrier();
    }
}

extern "C" void kernel_launch(void* const* d_in, const int* in_sizes, int n_in,
                              void* d_out, int out_size, void* d_ws, size_t ws_size,
                              hipStream_t stream)
{
    const float* x   = (const float*)d_in[0];
    const float* W1p = (const float*)d_in[1];
    const float* b1p = (const float*)d_in[2];
    const float* W1n = (const float*)d_in[3];
    const float* b1n = (const float*)d_in[4];
    const float* W2p = (const float*)d_in[5];
    const float* b2p = (const float*)d_in[6];
    const float* W2n = (const float*)d_in[7];
    const float* b2n = (const float*)d_in[8];
    const int*   pos = (const int*)d_in[9];
    const int*   neg = (const int*)d_in[10];

    int n = in_sizes[0] / 64;       // 100000
    int E = in_sizes[9] / 2;        // 1250000
    int n2 = 2 * n;

    // ws (4B units): deg[2n] cur[2n] bsum[1024] col[2E] xb[32n] zb[32n] A[64n]
    int*      deg  = (int*)d_ws;
    int*      cur  = deg + n2;
    int*      bsum = cur + n2;
    int*      col  = bsum + 1024;
    unsigned* xb   = (unsigned*)(col + 2 * (size_t)E);
    unsigned* zb   = xb + (size_t)n * 32;
    unsigned* Abuf = zb + (size_t)n * 32;

    hipMemsetAsync(deg, 0, (size_t)n2 * sizeof(int), stream);

    int eblocks = (2 * E + 255) / 256;
    int sblocks = (n2 + 255) / 256;

    cvt_k  <<<(n * 32 + 255) / 256, 256, 0, stream>>>((const float2*)x, xb, n * 32);
    hist_k <<<eblocks, 256, 0, stream>>>(pos, neg, deg, E, n);
    scan1_k<<<sblocks, 256, 0, stream>>>(deg, cur, bsum, n2);
    scan2_k<<<1, 1024, 0, stream>>>(bsum, sblocks);
    scan3_k<<<sblocks, 256, 0, stream>>>(cur, bsum, n2);
    int bpp = 128;
    fill_k <<<8 * bpp, 256, 0, stream>>>(pos, neg, cur, col, E, n, bpp);

    int gblocks = 2048;      // 8 blocks/CU, grid-stride over nodes
    int mblocks = (n / 16 + 3) / 4 + 1;   // one 16-node tile per wave

    gather_k<<<gblocks, 256, 0, stream>>>(xb, cur, col, Abuf, n);
    gemm_k<1><<<mblocks, 256, 0, stream>>>(Abuf, xb, W1p, b1p, W1n, b1n, zb, n);
    gather_k<<<gblocks, 256, 0, stream>>>(zb, cur, col, Abuf, n);
    gemm_k<2><<<mblocks, 256, 0, stream>>>(Abuf, zb, W2p, b2p, W2n, b2n, d_out, n);
}

// Round 7
// 547.983 us; speedup vs baseline: 1.0355x; 1.0355x over previous
//
#include <hip/hip_runtime.h>
#include <math.h>

// ---------------------------------------------------------------------------
// SGCN forward — R6b: R5 structure + cache-pollution control (compile fix:
// nt builtins need clang ext_vector_type, not HIP_vector_type structs).
//  * nt loads on all streaming reads (edge lists, col) so they stop evicting
//    L2 lines we care about (partially-filled col lines in fill_k; the
//    12.8MB bf16 feature table in gather_k). nt stores for Abuf.
//  * gemm grid 1564 -> 512 blocks: weight prologue 75MB -> 24MB.
//  * cvt fused into hist dispatch.
// ---------------------------------------------------------------------------

typedef __attribute__((ext_vector_type(8))) __bf16 bf16x8;
typedef __attribute__((ext_vector_type(4))) float f32x4;
typedef __attribute__((ext_vector_type(2))) unsigned uv2;
typedef __attribute__((ext_vector_type(4))) unsigned uv4;
typedef __attribute__((ext_vector_type(2))) float fv2;

__device__ inline unsigned bfpack(float lo, float hi) {
    unsigned a = __float_as_uint(lo), b = __float_as_uint(hi);
    a += 0x7fffu + ((a >> 16) & 1u);          // RNE to bf16
    b += 0x7fffu + ((b >> 16) & 1u);
    return (a >> 16) | (b & 0xffff0000u);
}
__device__ inline float bflo(unsigned p) { return __uint_as_float(p << 16); }
__device__ inline float bfhi(unsigned p) { return __uint_as_float(p & 0xffff0000u); }

__device__ inline float tanh_fast(float x) {
    float e = __builtin_amdgcn_exp2f(x * 2.8853900817779268f);
    return 1.0f - 2.0f * __builtin_amdgcn_rcpf(e + 1.0f);
}

__device__ inline bf16x8 as_frag(uv4 u) { return __builtin_bit_cast(bf16x8, u); }

// ------------------------------- CSR build ---------------------------------

// blocks [0, cvtBlocks): fp32 -> bf16-pair convert of x.
// blocks [cvtBlocks, ...): degree histogram with nt edge-stream reads.
__global__ void __launch_bounds__(256) pre_k(
    const fv2* __restrict__ xf, unsigned* __restrict__ xb, int m,
    const int* __restrict__ pos, const int* __restrict__ neg,
    int* __restrict__ deg, int E, int n, int cvtBlocks)
{
    if ((int)blockIdx.x < cvtBlocks) {
        int i = blockIdx.x * 256 + threadIdx.x;
        if (i < m) {
            fv2 v = __builtin_nontemporal_load(&xf[i]);
            xb[i] = bfpack(v.x, v.y);
        }
    } else {
        int e = (blockIdx.x - cvtBlocks) * 256 + threadIdx.x;
        if (e < E)
            atomicAdd(&deg[__builtin_nontemporal_load(&pos[E + e])], 1);
        else if (e < 2 * E)
            atomicAdd(&deg[n + __builtin_nontemporal_load(&neg[E + (e - E)])], 1);
    }
}

__global__ void __launch_bounds__(256) scan1_k(
    const int* __restrict__ deg, int* __restrict__ cur,
    int* __restrict__ bsum, int n2)
{
    __shared__ int s[256];
    int tid = threadIdx.x;
    int i = blockIdx.x * 256 + tid;
    int v = (i < n2) ? deg[i] : 0;
    s[tid] = v;
    __syncthreads();
    for (int off = 1; off < 256; off <<= 1) {
        int t = (tid >= off) ? s[tid - off] : 0;
        __syncthreads();
        s[tid] += t;
        __syncthreads();
    }
    if (i < n2) cur[i] = s[tid] - v;
    if (tid == 255) bsum[blockIdx.x] = s[255];
}

__global__ void __launch_bounds__(1024) scan2_k(int* __restrict__ bsum, int nb)
{
    __shared__ int s[1024];
    int tid = threadIdx.x;
    int v = (tid < nb) ? bsum[tid] : 0;
    s[tid] = v;
    __syncthreads();
    for (int off = 1; off < 1024; off <<= 1) {
        int t = (tid >= off) ? s[tid - off] : 0;
        __syncthreads();
        s[tid] += t;
        __syncthreads();
    }
    if (tid < nb) bsum[tid] = s[tid] - v;
}

__global__ void __launch_bounds__(256) scan3_k(
    int* __restrict__ cur, const int* __restrict__ bsum, int n2)
{
    int i = blockIdx.x * 256 + threadIdx.x;
    if (i < n2) cur[i] += bsum[blockIdx.x];
}

// XCD-partitioned fill; nt loads keep the 8x edge re-stream from evicting
// the partially-filled col lines out of each XCD's L2.
__global__ void __launch_bounds__(256) fill_k(
    const int* __restrict__ pos, const int* __restrict__ neg,
    int* __restrict__ cur, int* __restrict__ col, int E, int n,
    int blocksPerPart)
{
    int part = blockIdx.x & 7;
    int wb   = blockIdx.x >> 3;
    int n2 = 2 * n;
    int lo = (int)(((long long)n2 * part) >> 3);
    int hi = (int)(((long long)n2 * (part + 1)) >> 3);
    int stride = blocksPerPart * 256;
    for (int e = wb * 256 + (int)threadIdx.x; e < 2 * E; e += stride) {
        int node;
        if (e < E) node = __builtin_nontemporal_load(&pos[E + e]);
        else       node = n + __builtin_nontemporal_load(&neg[E + (e - E)]);
        if (node >= lo && node < hi) {
            int src = (e < E) ? __builtin_nontemporal_load(&pos[e])
                              : __builtin_nontemporal_load(&neg[e - E]);
            int slot = atomicAdd(&cur[node], 1);
            col[slot] = src;
        }
    }
}

// ----------------------------- pull gather ---------------------------------
// One wave per node (grid-stride). lane = 16g+f: group g handles edges
// p0+4k+g, f indexes an 8-byte (4-feature) chunk of the 128B bf16 row.
// col stream is nt (read-once) so the bf16 table stays L2-resident.
__global__ void __launch_bounds__(256, 8) gather_k(
    const unsigned* __restrict__ tab,   // n x 32 uints (bf16 pairs)
    const int* __restrict__ cur, const int* __restrict__ col,
    unsigned* __restrict__ Aout,        // n x 64 uints
    int n)
{
    int tid = threadIdx.x;
    int wave = tid >> 6, lane = tid & 63, g = lane >> 4, f = lane & 15;
    int stride = gridDim.x * 4;
    for (int node = blockIdx.x * 4 + wave; node < n; node += stride) {
        int p0 = node ? cur[node - 1] : 0;
        int p1 = cur[node];
        int q0 = cur[n + node - 1];     // node==0 -> cur[n-1] == E
        int q1 = cur[n + node];
        float a0 = 0.f, a1 = 0.f, a2 = 0.f, a3 = 0.f;
        float b0 = 0.f, b1 = 0.f, b2 = 0.f, b3 = 0.f;
        #pragma unroll 2
        for (int it = p0 + g; it < p1; it += 4) {
            int s = __builtin_nontemporal_load(&col[it]);
            uv2 t = *(const uv2*)(tab + (size_t)s * 32 + 2 * f);
            a0 += bflo(t.x); a1 += bfhi(t.x); a2 += bflo(t.y); a3 += bfhi(t.y);
        }
        #pragma unroll 2
        for (int it = q0 + g; it < q1; it += 4) {
            int s = __builtin_nontemporal_load(&col[it]);
            uv2 t = *(const uv2*)(tab + (size_t)s * 32 + 2 * f);
            b0 += bflo(t.x); b1 += bfhi(t.x); b2 += bflo(t.y); b3 += bfhi(t.y);
        }
        a0 += __shfl_xor(a0, 16); a1 += __shfl_xor(a1, 16);
        a2 += __shfl_xor(a2, 16); a3 += __shfl_xor(a3, 16);
        b0 += __shfl_xor(b0, 16); b1 += __shfl_xor(b1, 16);
        b2 += __shfl_xor(b2, 16); b3 += __shfl_xor(b3, 16);
        a0 += __shfl_xor(a0, 32); a1 += __shfl_xor(a1, 32);
        a2 += __shfl_xor(a2, 32); a3 += __shfl_xor(a3, 32);
        b0 += __shfl_xor(b0, 32); b1 += __shfl_xor(b1, 32);
        b2 += __shfl_xor(b2, 32); b3 += __shfl_xor(b3, 32);
        float rp = 1.0f / (float)max(p1 - p0, 1);
        float rq = 1.0f / (float)max(q1 - q0, 1);
        if (g == 0) {
            uv2 o; o.x = bfpack(a0 * rp, a1 * rp); o.y = bfpack(a2 * rp, a3 * rp);
            __builtin_nontemporal_store(o, (uv2*)(Aout + (size_t)node * 64 + 2 * f));
        } else if (g == 1) {
            uv2 o; o.x = bfpack(b0 * rq, b1 * rq); o.y = bfpack(b2 * rq, b3 * rq);
            __builtin_nontemporal_store(o, (uv2*)(Aout + (size_t)node * 64 + 32 + 2 * f));
        }
    }
}

// ------------------------------ MFMA dense ---------------------------------
template<int LAYER>
__global__ void __launch_bounds__(256, 2) gemm_k(
    const unsigned* __restrict__ A,      // n x 64 uints  [agg_p|agg_n]
    const unsigned* __restrict__ T,      // n x 32 uints  (x or z bf16)
    const float* __restrict__ Wp, const float* __restrict__ bp,
    const float* __restrict__ Wn, const float* __restrict__ bn,
    void* __restrict__ outv, int n)
{
    __shared__ unsigned short Bl[64 * 200];   // 25.6 KB
    __shared__ float Cs[4][16 * 68];          // 17.4 KB, per-wave C transpose
    int tid = threadIdx.x;
    for (int idx = tid; idx < 64 * 192; idx += 256) {
        int k = idx >> 6, nn = idx & 63;
        float v = 0.f;
        if (LAYER == 1) {
            if (nn < 32) { if (k < 64) v = Wp[k * 32 + nn];
                           else if (k >= 128) v = Wp[(k - 64) * 32 + nn]; }
            else         { if (k >= 64) v = Wn[(k - 64) * 32 + (nn - 32)]; }
        } else {
            if (nn < 32) { if (k < 32) v = Wp[k * 32 + nn];
                           else if (k >= 96 && k < 160) v = Wp[(k - 64) * 32 + nn]; }
            else         { if (k >= 32 && k < 96) v = Wn[(k - 32) * 32 + (nn - 32)];
                           else if (k >= 160) v = Wn[(k - 96) * 32 + (nn - 32)]; }
        }
        unsigned u = __float_as_uint(v);
        u += 0x7fffu + ((u >> 16) & 1u);
        Bl[nn * 200 + k] = (unsigned short)(u >> 16);
    }
    __syncthreads();

    int wave = tid >> 6, lane = tid & 63;
    int lm = lane & 15, lg = lane >> 4;

    bf16x8 Bf[4][6];
    #pragma unroll
    for (int t = 0; t < 4; ++t)
        #pragma unroll
        for (int s = 0; s < 6; ++s)
            Bf[t][s] = *(const bf16x8*)&Bl[(t * 16 + lm) * 200 + s * 32 + lg * 8];

    float bias[4];
    #pragma unroll
    for (int t = 0; t < 4; ++t) {
        int nc = t * 16 + lm;
        bias[t] = (nc < 32) ? bp[nc] : bn[nc - 32];
    }

    float* Cw = Cs[wave];
    int ntiles = (n + 15) >> 4;
    for (int tile = blockIdx.x * 4 + wave; tile < ntiles; tile += gridDim.x * 4) {
        int node0 = tile * 16;
        int ra = min(node0 + lm, n - 1);          // A-frag: m = lane&15
        const uv4* Arow = (const uv4*)(A + (size_t)ra * 64);
        const uv4* Trow = (const uv4*)(T + (size_t)ra * 32);
        bf16x8 Af[6];
        #pragma unroll
        for (int s = 0; s < 4; ++s)
            Af[s] = as_frag(__builtin_nontemporal_load(&Arow[s * 4 + lg]));
        #pragma unroll
        for (int s = 0; s < 2; ++s) Af[4 + s] = as_frag(Trow[s * 4 + lg]);

        #pragma unroll
        for (int t = 0; t < 4; ++t) {
            f32x4 c = {0.f, 0.f, 0.f, 0.f};
            #pragma unroll
            for (int s = 0; s < 6; ++s)
                c = __builtin_amdgcn_mfma_f32_16x16x32_bf16(Af[s], Bf[t][s], c, 0, 0, 0);
            #pragma unroll
            for (int r = 0; r < 4; ++r)
                Cw[(lg * 4 + r) * 68 + t * 16 + lm] = tanh_fast(c[r] + bias[t]);
        }
        __builtin_amdgcn_wave_barrier();
        if (LAYER == 1) {
            unsigned* zb = (unsigned*)outv;
            #pragma unroll
            for (int i = 0; i < 8; ++i) {
                int nn = 2 * i + (lane >> 5), cc = lane & 31;
                int node = node0 + nn;
                if (node < n) {
                    float2 rd = *(const float2*)&Cw[nn * 68 + 2 * cc];
                    zb[(size_t)node * 32 + cc] = bfpack(rd.x, rd.y);
                }
            }
        } else {
            float* out = (float*)outv;
            #pragma unroll
            for (int i = 0; i < 16; ++i) {
                int node = node0 + i;
                if (node < n) out[(size_t)node * 64 + lane] = Cw[i * 68 + lane];
            }
        }
        __builtin_amdgcn_wave_barrier();
    }
}

extern "C" void kernel_launch(void* const* d_in, const int* in_sizes, int n_in,
                              void* d_out, int out_size, void* d_ws, size_t ws_size,
                              hipStream_t stream)
{
    const float* x   = (const float*)d_in[0];
    const float* W1p = (const float*)d_in[1];
    const float* b1p = (const float*)d_in[2];
    const float* W1n = (const float*)d_in[3];
    const float* b1n = (const float*)d_in[4];
    const float* W2p = (const float*)d_in[5];
    const float* b2p = (const float*)d_in[6];
    const float* W2n = (const float*)d_in[7];
    const float* b2n = (const float*)d_in[8];
    const int*   pos = (const int*)d_in[9];
    const int*   neg = (const int*)d_in[10];

    int n = in_sizes[0] / 64;       // 100000
    int E = in_sizes[9] / 2;        // 1250000
    int n2 = 2 * n;

    // ws (4B units): deg[2n] cur[2n] bsum[1024] col[2E] xb[32n] zb[32n] A[64n]
    int*      deg  = (int*)d_ws;
    int*      cur  = deg + n2;
    int*      bsum = cur + n2;
    int*      col  = bsum + 1024;
    unsigned* xb   = (unsigned*)(col + 2 * (size_t)E);
    unsigned* zb   = xb + (size_t)n * 32;
    unsigned* Abuf = zb + (size_t)n * 32;

    (void)hipMemsetAsync(deg, 0, (size_t)n2 * sizeof(int), stream);

    int eblocks = (2 * E + 255) / 256;
    int sblocks = (n2 + 255) / 256;
    int cvtBlocks = (n * 32 + 255) / 256;

    pre_k  <<<cvtBlocks + eblocks, 256, 0, stream>>>((const fv2*)x, xb, n * 32,
                                                     pos, neg, deg, E, n, cvtBlocks);
    scan1_k<<<sblocks, 256, 0, stream>>>(deg, cur, bsum, n2);
    scan2_k<<<1, 1024, 0, stream>>>(bsum, sblocks);
    scan3_k<<<sblocks, 256, 0, stream>>>(cur, bsum, n2);
    int bpp = 128;
    fill_k <<<8 * bpp, 256, 0, stream>>>(pos, neg, cur, col, E, n, bpp);

    int gblocks = 2048;      // 8 blocks/CU, grid-stride over nodes
    int mblocks = 512;       // gemm: ~3 tiles/wave, prologue amortized

    gather_k<<<gblocks, 256, 0, stream>>>(xb, cur, col, Abuf, n);
    gemm_k<1><<<mblocks, 256, 0, stream>>>(Abuf, xb, W1p, b1p, W1n, b1n, zb, n);
    gather_k<<<gblocks, 256, 0, stream>>>(zb, cur, col, Abuf, n);
    gemm_k<2><<<mblocks, 256, 0, stream>>>(Abuf, zb, W2p, b2p, W2n, b2n, d_out, n);
}